// Round 3
// baseline (4234.471 us; speedup 1.0000x reference)
//
#include <hip/hip_runtime.h>
#include <hip/hip_fp16.h>
#include <cstdint>
#include <cstddef>

typedef _Float16 half_t;
typedef _Float16 half2_t __attribute__((ext_vector_type(2)));
typedef _Float16 half8_t __attribute__((ext_vector_type(8)));
typedef float    f32x4   __attribute__((ext_vector_type(4)));

#define T_FULL  2048
#define T_CH    512
#define N_CHUNK 4
#define B_SZ    64
#define H_SZ    256
#define G4      1024
#define CH_M    (B_SZ * T_CH)   // 32768

// Per hh-half (64 k-pairs): 50 register-resident, 14 LDS-resident, 0 streamed
#define KP_RF   50
#define KP_LDS  14

// ---------------- workspace layout (bytes) ----------------
static constexpr size_t OFF_XW   = 0;                                   // half [CH_M][1024] (i,f,g,o)x256
static constexpr size_t OFF_H    = OFF_XW   + (size_t)CH_M * G4 * 2;    // half [CH_M][256]
static constexpr size_t OFF_WIH  = OFF_H    + (size_t)CH_M * H_SZ * 2;  // half [1024][256]  (B^T)
static constexpr size_t OFF_WOUT = OFF_WIH  + (size_t)G4 * 256 * 2;     // half [256][256]   (B^T)
static constexpr size_t OFF_WRF  = OFF_WOUT + (size_t)256 * 256 * 2;    // uint [2][50][1024]
static constexpr size_t OFF_WLDS = OFF_WRF  + (size_t)2 * KP_RF * 1024 * 4;   // uint4 [2][14][256]
static constexpr size_t OFF_SC   = OFF_WLDS + (size_t)2 * KP_LDS * 256 * 16;  // float [64][256]
static constexpr size_t OFF_SH   = OFF_SC   + (size_t)B_SZ * H_SZ * 4;  // uint [64][128] f16 pairs

// ---------------- helpers ----------------
__device__ __forceinline__ unsigned int packh2(float a, float b) {
    half2_t h; h.x = (half_t)a; h.y = (half_t)b;
    return __builtin_bit_cast(unsigned int, h);
}

__device__ __forceinline__ float dot2f(unsigned int hp, unsigned int wp, float acc) {
#if __has_builtin(__builtin_amdgcn_fdot2)
    return __builtin_amdgcn_fdot2(__builtin_bit_cast(half2_t, hp),
                                  __builtin_bit_cast(half2_t, wp), acc, false);
#else
    half2_t h = __builtin_bit_cast(half2_t, hp);
    half2_t w = __builtin_bit_cast(half2_t, wp);
    return fmaf((float)h.y, (float)w.y, fmaf((float)h.x, (float)w.x, acc));
#endif
}

__device__ __forceinline__ unsigned int rlane(unsigned int v, int lane) {
    return (unsigned int)__builtin_amdgcn_readlane((int)v, lane);
}

__device__ __forceinline__ float sigm(float x)  { return 1.0f / (1.0f + __expf(-x)); }
__device__ __forceinline__ float tanh_(float x) { return 1.0f - 2.0f / (__expf(2.0f * x) + 1.0f); }

// ---------------- K0: pack weights + init state ----------------
// sections: wih 262144 | wout 65536 | rf 102400 | lds 28672 | c 16384 | h 8192
static constexpr int PACK_TOTAL = 262144 + 65536 + 2 * KP_RF * 1024
                                + 2 * KP_LDS * 256 * 4 + 16384 + 8192;

__global__ __launch_bounds__(256) void pack_kernel(
    const float* __restrict__ Wih, const float* __restrict__ Whh,
    const float* __restrict__ Wout, const float* __restrict__ c0,
    const float* __restrict__ h0,
    half_t* __restrict__ wih_t, half_t* __restrict__ wout_t,
    unsigned int* __restrict__ whh_rf, unsigned int* __restrict__ whh_lds,
    float* __restrict__ state_c, unsigned int* __restrict__ state_h)
{
    const int stride = gridDim.x * blockDim.x;
    for (int idx = blockIdx.x * blockDim.x + threadIdx.x; idx < PACK_TOTAL; idx += stride) {
        int r = idx;
        if (r < 262144) {                       // wih_t[n][k] = Wih[k][n]
            int n = r >> 8, k = r & 255;
            wih_t[r] = (half_t)Wih[k * 1024 + n];
            continue;
        }
        r -= 262144;
        if (r < 65536) {                        // wout_t[n][k] = Wout[k][n]
            int n = r >> 8, k = r & 255;
            wout_t[r] = (half_t)Wout[k * 256 + n];
            continue;
        }
        r -= 65536;
        if (r < 2 * KP_RF * 1024) {             // whh_rf[hh][pl][col], p = hh*64+pl, k=2p
            int col = r & 1023, q2 = r >> 10;
            int hh = q2 / KP_RF, pl = q2 % KP_RF;
            int k0 = 2 * (hh * 64 + pl);
            whh_rf[r] = packh2(Whh[k0 * 1024 + col], Whh[(k0 + 1) * 1024 + col]);
            continue;
        }
        r -= 2 * KP_RF * 1024;
        if (r < 2 * KP_LDS * 256 * 4) {         // whh_lds[hh][ql][e].j  col=j*256+e, p=hh*64+50+ql
            int j = r & 3, e = (r >> 2) & 255, rest = r >> 10;
            int ql = rest % KP_LDS, hh = rest / KP_LDS;
            int k0 = 2 * (hh * 64 + KP_RF + ql);
            int col = j * 256 + e;
            whh_lds[r] = packh2(Whh[k0 * 1024 + col], Whh[(k0 + 1) * 1024 + col]);
            continue;
        }
        r -= 2 * KP_LDS * 256 * 4;
        if (r < 16384) { state_c[r] = c0[r]; continue; }
        r -= 16384;
        state_h[r] = packh2(h0[2 * r], h0[2 * r + 1]);
    }
}

// ---------------- K1/K3: f16 MFMA GEMM, 128x128 tile, K=256 ----------------
template<int AMODE, int CMODE>
__global__ __launch_bounds__(256) void gemm16(
    const void* __restrict__ Ap, const half_t* __restrict__ Bt,
    void* __restrict__ Cp, const float* __restrict__ bias, int chunk0)
{
    __shared__ half_t Als[128][40];
    __shared__ half_t Bls[128][40];
    const int tid  = threadIdx.x;
    const int lane = tid & 63, wid = tid >> 6;
    const int wr = wid >> 1, wc = wid & 1;
    const int m0 = blockIdx.x * 128, n0 = blockIdx.y * 128;

    f32x4 acc[4][4] = {};

    for (int kc = 0; kc < 8; ++kc) {
        __syncthreads();
        if (AMODE == 1) {
            const float* A = (const float*)Ap;
            #pragma unroll
            for (int i = 0; i < 4; ++i) {
                int l = tid + i * 256;
                int row = l >> 3, kq = l & 7;
                int m = m0 + row;
                int arow = ((m >> 9) << 11) + chunk0 + (m & 511);
                f32x4 v = *(const f32x4*)(A + (size_t)arow * 256 + kc * 32 + kq * 4);
                uint2 pk;
                pk.x = packh2(v.x, v.y);
                pk.y = packh2(v.z, v.w);
                *reinterpret_cast<uint2*>(&Als[row][kq * 4]) = pk;
            }
        } else {
            const half_t* A = (const half_t*)Ap;
            #pragma unroll
            for (int i = 0; i < 2; ++i) {
                int l = tid + i * 256;
                int row = l >> 2, ko = l & 3;
                half8_t v = *(const half8_t*)(A + (size_t)(m0 + row) * 256 + kc * 32 + ko * 8);
                *reinterpret_cast<half8_t*>(&Als[row][ko * 8]) = v;
            }
        }
        #pragma unroll
        for (int i = 0; i < 2; ++i) {
            int l = tid + i * 256;
            int row = l >> 2, ko = l & 3;
            half8_t v = *(const half8_t*)(Bt + (size_t)(n0 + row) * 256 + kc * 32 + ko * 8);
            *reinterpret_cast<half8_t*>(&Bls[row][ko * 8]) = v;
        }
        __syncthreads();

        half8_t af[4], bf[4];
        #pragma unroll
        for (int mi = 0; mi < 4; ++mi)
            af[mi] = *reinterpret_cast<const half8_t*>(&Als[wr * 64 + mi * 16 + (lane & 15)][(lane >> 4) * 8]);
        #pragma unroll
        for (int ni = 0; ni < 4; ++ni)
            bf[ni] = *reinterpret_cast<const half8_t*>(&Bls[wc * 64 + ni * 16 + (lane & 15)][(lane >> 4) * 8]);
        #pragma unroll
        for (int mi = 0; mi < 4; ++mi)
            #pragma unroll
            for (int ni = 0; ni < 4; ++ni)
                acc[mi][ni] = __builtin_amdgcn_mfma_f32_16x16x32_f16(af[mi], bf[ni], acc[mi][ni], 0, 0, 0);
    }

    #pragma unroll
    for (int mi = 0; mi < 4; ++mi) {
        #pragma unroll
        for (int ni = 0; ni < 4; ++ni) {
            #pragma unroll
            for (int reg = 0; reg < 4; ++reg) {
                int row = m0 + wr * 64 + mi * 16 + (lane >> 4) * 4 + reg;   // m
                int col = n0 + wc * 64 + ni * 16 + (lane & 15);             // n
                float v = acc[mi][ni][reg] + bias[col];
                if (CMODE == 0) {
                    ((half_t*)Cp)[(size_t)row * 1024 + ((col & 255) << 2) + (col >> 8)] = (half_t)v;
                } else {
                    int crow = ((row >> 9) << 11) + chunk0 + (row & 511);
                    ((float*)Cp)[(size_t)crow * 256 + col] = v;
                }
            }
        }
    }
}

// ---------------- K2: per-chain recurrent LSTM, K-split across 512 threads ----------------
// thread (e = t&255, hh = t>>8): all 4 gate cols of element e, k-half hh.
// Whh fully resident: 50 pairs/half in VGPRs, 14 pairs/half in LDS. No per-step
// global weight traffic. __launch_bounds__(512,1): full 256 arch-VGPR budget,
// HW still runs 2 waves/SIMD (2 x 256 = 512-reg pool).
__global__ __launch_bounds__(512, 1) void rnn_kernel(
    const unsigned int* __restrict__ whh_rf,
    const uint4* __restrict__ whh_lds,
    const half_t* __restrict__ xw,
    half_t* __restrict__ h_out,
    float* __restrict__ state_c,
    unsigned int* __restrict__ state_h)
{
    __shared__ uint4  lds_w[2 * KP_LDS * 256];   // 114688 B
    __shared__ float4 gbuf[256];                 // 4096 B
    __shared__ unsigned int hbuf[128];           // 512 B

    const int t    = threadIdx.x;
    const int e    = t & 255;
    const int hh   = t >> 8;
    const int lane = t & 63;
    const int b    = blockIdx.x;

    for (int i = t; i < 2 * KP_LDS * 256; i += 512) lds_w[i] = whh_lds[i];
    if (t < 128) hbuf[t] = state_h[b * 128 + t];
    float c = (hh == 0) ? state_c[b * 256 + e] : 0.0f;

    // register-resident Whh: k-pairs (hh*64 + 0..49) x 4 gate cols {e,256+e,512+e,768+e}
    unsigned int wreg[KP_RF][4];
    {
        const unsigned int* wrp = whh_rf + hh * (KP_RF * 1024) + e;
        #pragma unroll
        for (int pl = 0; pl < KP_RF; ++pl)
            #pragma unroll
            for (int j = 0; j < 4; ++j)
                wreg[pl][j] = wrp[pl * 1024 + j * 256];
    }
    __syncthreads();

    const half_t* xwp = xw + (size_t)b * T_CH * 1024 + e * 4;
    half_t* hop = h_out + (size_t)b * T_CH * 256 + e;
    const uint4* ldp  = lds_w + hh * (KP_LDS * 256) + e;

    // prologue: h broadcast source for step 0 (pairs hh*64 .. hh*64+63)
    unsigned int hv = hbuf[hh * 64 + lane];

    for (int step = 0; step < T_CH; ++step) {
        // long-latency xw load issued early, consumed after barrier
        uint2 xv = {0, 0};
        if (hh == 0) xv = *(const uint2*)xwp;

        float a0 = 0.f, a1 = 0.f, a2 = 0.f, a3 = 0.f;

        // RF part: local k-pairs 0..49
        #pragma unroll
        for (int pl = 0; pl < KP_RF; ++pl) {
            unsigned int s = rlane(hv, pl);
            a0 = dot2f(s, wreg[pl][0], a0);
            a1 = dot2f(s, wreg[pl][1], a1);
            a2 = dot2f(s, wreg[pl][2], a2);
            a3 = dot2f(s, wreg[pl][3], a3);
        }
        // LDS part: local k-pairs 50..63
        #pragma unroll
        for (int ql = 0; ql < KP_LDS; ++ql) {
            uint4 q = ldp[ql * 256];
            unsigned int s = rlane(hv, KP_RF + ql);
            a0 = dot2f(s, q.x, a0);
            a1 = dot2f(s, q.y, a1);
            a2 = dot2f(s, q.z, a2);
            a3 = dot2f(s, q.w, a3);
        }

        if (hh) {
            float4 p; p.x = a0; p.y = a1; p.z = a2; p.w = a3;
            gbuf[e] = p;
        }
        __syncthreads();   // gbuf write -> read; hbuf read -> write

        if (hh == 0) {
            float4 p = gbuf[e];
            half2_t x0 = __builtin_bit_cast(half2_t, xv.x);
            half2_t x1 = __builtin_bit_cast(half2_t, xv.y);
            a0 += p.x + (float)x0.x;
            a1 += p.y + (float)x0.y;
            a2 += p.z + (float)x1.x;
            a3 += p.w + (float)x1.y;
            float ig = sigm(a0), fg = sigm(a1), gg = tanh_(a2), og = sigm(a3);
            c = fg * c + ig * gg;
            float hn = og * tanh_(c);
            half_t h16 = (half_t)hn;
            reinterpret_cast<half_t*>(hbuf)[e] = h16;
            *hop = h16;
        }
        xwp += 1024;
        hop += 256;
        __syncthreads();   // hbuf write -> next read; gbuf read -> next write
        hv = hbuf[hh * 64 + lane];   // prefetch next step's h broadcast
    }

    if (hh == 0) state_c[b * 256 + e] = c;
    if (t < 128) state_h[b * 128 + t] = hbuf[t];
}

// ---------------- launch ----------------
extern "C" void kernel_launch(void* const* d_in, const int* in_sizes, int n_in,
                              void* d_out, int out_size, void* d_ws, size_t ws_size,
                              hipStream_t stream) {
    const float* x    = (const float*)d_in[0];
    const float* c0   = (const float*)d_in[1];
    const float* h0   = (const float*)d_in[2];
    const float* Wih  = (const float*)d_in[3];
    const float* Whh  = (const float*)d_in[4];
    const float* bh   = (const float*)d_in[5];
    const float* Wout = (const float*)d_in[6];
    const float* bout = (const float*)d_in[7];

    char* ws = (char*)d_ws;
    half_t* xw             = (half_t*)(ws + OFF_XW);
    half_t* h_chunk        = (half_t*)(ws + OFF_H);
    half_t* wih_t          = (half_t*)(ws + OFF_WIH);
    half_t* wout_t         = (half_t*)(ws + OFF_WOUT);
    unsigned int* whh_rf   = (unsigned int*)(ws + OFF_WRF);
    unsigned int* whh_lds  = (unsigned int*)(ws + OFF_WLDS);
    float* state_c         = (float*)(ws + OFF_SC);
    unsigned int* state_h  = (unsigned int*)(ws + OFF_SH);

    pack_kernel<<<512, 256, 0, stream>>>(Wih, Whh, Wout, c0, h0,
                                         wih_t, wout_t, whh_rf, whh_lds,
                                         state_c, state_h);

    for (int ch = 0; ch < N_CHUNK; ++ch) {
        int chunk0 = ch * T_CH;
        gemm16<1, 0><<<dim3(CH_M / 128, G4 / 128), 256, 0, stream>>>(
            (const void*)x, wih_t, (void*)xw, bh, chunk0);
        rnn_kernel<<<B_SZ, 512, 0, stream>>>(whh_rf, (const uint4*)whh_lds,
                                             xw, h_chunk, state_c, state_h);
        gemm16<0, 1><<<dim3(CH_M / 128, H_SZ / 128), 256, 0, stream>>>(
            (const void*)h_chunk, wout_t, d_out, bout, chunk0);
    }
    (void)in_sizes; (void)n_in; (void)out_size; (void)ws_size;
}